// Round 12
// baseline (300.680 us; speedup 1.0000x reference)
//
#include <hip/hip_runtime.h>
#include <hip/hip_bf16.h>
#include <cstdint>
#include <cstddef>

// ---- problem constants ----
constexpr int SEQ   = 4096;
constexpr int HIDN  = 2048;
constexpr int NHEAD = 8;
constexpr int NKVH  = 4;
constexpr int DH    = 256;
constexpr int NPROJ = 2624;      // 48 + 8 + 8 + 1536 + 512 + 512
constexpr int NPROJP= 2688;      // padded to /128
constexpr int WIN   = 1024;

typedef __attribute__((ext_vector_type(4))) float f32x4;
typedef __attribute__((ext_vector_type(8))) short bf16x8;
typedef __attribute__((ext_vector_type(4))) short bf16x4;
typedef unsigned short u16;

__device__ __forceinline__ u16 f2bf(float x) {
  union { float f; uint32_t u; } v; v.f = x;
  uint32_t r = v.u + 0x7fffu + ((v.u >> 16) & 1u);
  return (u16)(r >> 16);
}
__device__ __forceinline__ float bf2f(u16 v) {
  union { uint32_t u; float f; } w; w.u = (uint32_t)v << 16; return w.f;
}

__device__ __forceinline__ uint32_t cvtpk(float lo, float hi) {
  uint32_t r;
  asm("v_cvt_pk_bf16_f32 %0, %1, %2" : "=v"(r) : "v"(lo), "v"(hi));
  return r;
}

// async global->LDS, 16B per lane, dest = wave-uniform base + lane*16 (linear)
__device__ __forceinline__ void gl_lds16(const u16* g, u16* l) {
  __builtin_amdgcn_global_load_lds(
      (const __attribute__((address_space(1))) uint32_t*)g,
      (__attribute__((address_space(3))) uint32_t*)l, 16, 0, 0);
}

// barrier draining only VMEM (staged gl_lds); nothing else pinned
__device__ __forceinline__ void sync_vm() {
  asm volatile("s_waitcnt vmcnt(0)" ::: "memory");
  __builtin_amdgcn_s_barrier();
  __builtin_amdgcn_sched_barrier(0);
}

// barrier draining LDS reads (rule #18: lgkmcnt + sched fence BEFORE s_barrier
// so no wave can overwrite single-buffered LDS while another's reads are live)
__device__ __forceinline__ void sync_lgkm() {
  asm volatile("s_waitcnt lgkmcnt(0)" ::: "memory");
  __builtin_amdgcn_sched_barrier(0);
  __builtin_amdgcn_s_barrier();
  __builtin_amdgcn_sched_barrier(0);
}

// bijective XCD-aware workgroup remap (m204)
__device__ __forceinline__ int xcd_swz(int wg, int nwg) {
  const int q = nwg >> 3, r = nwg & 7;
  const int xcd = wg & 7, lo = wg >> 3;
  return (xcd < r ? xcd * (q + 1) : r * (q + 1) + (xcd - r) * q) + lo;
}

// ---------------- f32 -> bf16 convert (vectorized x4) ----------------
__global__ __launch_bounds__(256) void k_cvt(const float* __restrict__ src,
                                             u16* __restrict__ dst, int n4) {
  int i = blockIdx.x * 256 + threadIdx.x;
  if (i >= n4) return;
  float4 v = ((const float4*)src)[i];
  ushort4 o; o.x = f2bf(v.x); o.y = f2bf(v.y); o.z = f2bf(v.z); o.w = f2bf(v.w);
  ((ushort4*)dst)[i] = o;
}

// ---------------- build concatenated projection weight (bf16, padded) ----------------
__global__ __launch_bounds__(256) void k_wcat(
    const float* __restrict__ waq, const float* __restrict__ wak,
    const float* __restrict__ wav, const float* __restrict__ wbq,
    const float* __restrict__ wbk, const float* __restrict__ wbv,
    u16* __restrict__ wcat) {
  const int r = blockIdx.x;
  const int col0 = threadIdx.x * 8;
  u16* out = wcat + (size_t)r * HIDN + col0;
  const float* src = nullptr; int rr = 0;
  if      (r < 48)   { src = waq; rr = r; }
  else if (r < 56)   { src = wak; rr = r - 48; }
  else if (r < 64)   { src = wav; rr = r - 56; }
  else if (r < 1600) { src = wbq; rr = r - 64; }
  else if (r < 2112) { src = wbk; rr = r - 1600; }
  else if (r < 2624) { src = wbv; rr = r - 2112; }
  if (!src) {
    ushort4 z = {0,0,0,0}; ((ushort4*)out)[0] = z; ((ushort4*)out)[1] = z; return;
  }
  const float* s = src + (size_t)rr * HIDN + col0;
#pragma unroll
  for (int i = 0; i < 2; ++i) {
    float4 v = ((const float4*)s)[i];
    ushort4 o; o.x = f2bf(v.x); o.y = f2bf(v.y); o.z = f2bf(v.z); o.w = f2bf(v.w);
    ((ushort4*)out)[i] = o;
  }
}

// ---------------- bf16 GEMM: C(MxN) = A(MxK) @ B(NxK)^T (R4/R6 best) ----------------
template<int OBF16>
__global__ __launch_bounds__(256)
void k_gemm_bt(const u16* __restrict__ A, const u16* __restrict__ Bm,
               void* __restrict__ Cv, int M, int N, int K) {
  __shared__ u16 lA[2][128 * 32];
  __shared__ u16 lB[2][128 * 32];
  const int tid = threadIdx.x;
  const int wid = tid >> 6, lane = tid & 63;
  const int l15 = lane & 15, g = lane >> 4;
  const int nwg = gridDim.x * gridDim.y;
  int wg = xcd_swz(blockIdx.y * gridDim.x + blockIdx.x, nwg);
  const int m0 = (wg / gridDim.x) * 128, n0 = (wg % gridDim.x) * 128;
  const int wr = wid >> 1, wc = wid & 1;
  f32x4 acc[4][4];
#pragma unroll
  for (int m = 0; m < 4; ++m)
#pragma unroll
    for (int n = 0; n < 4; ++n) acc[m][n] = (f32x4){0.f,0.f,0.f,0.f};
  const int NT = K >> 5;

  auto stage = [&](int buf, int kt) {
    const int k0 = kt << 5;
#pragma unroll
    for (int i = 0; i < 2; ++i) {
      const int u = i * 256 + tid;
      const int row = u >> 2, cs = u & 3;
      const int cc = cs ^ ((row >> 1) & 3);
      gl_lds16(A  + (size_t)(m0 + row) * K + k0 + cc * 8, &lA[buf][(i*256 + wid*64) * 8]);
      gl_lds16(Bm + (size_t)(n0 + row) * K + k0 + cc * 8, &lB[buf][(i*256 + wid*64) * 8]);
    }
  };

  stage(0, 0);
  int cur = 0;
  for (int kt = 0; kt < NT; ++kt) {
    __syncthreads();
    if (kt + 1 < NT) stage(cur ^ 1, kt + 1);
    bf16x8 af[4], bfr[4];
#pragma unroll
    for (int m = 0; m < 4; ++m) {
      const int row = wr*64 + m*16 + l15;
      const int cc = g ^ ((row >> 1) & 3);
      af[m] = *(const bf16x8*)&lA[cur][row*32 + cc*8];
    }
#pragma unroll
    for (int n = 0; n < 4; ++n) {
      const int row = wc*64 + n*16 + l15;
      const int cc = g ^ ((row >> 1) & 3);
      bfr[n] = *(const bf16x8*)&lB[cur][row*32 + cc*8];
    }
    __builtin_amdgcn_s_setprio(1);
#pragma unroll
    for (int m = 0; m < 4; ++m)
#pragma unroll
      for (int n = 0; n < 4; ++n)
        acc[m][n] = __builtin_amdgcn_mfma_f32_16x16x32_bf16(af[m], bfr[n], acc[m][n], 0, 0, 0);
    __builtin_amdgcn_s_setprio(0);
    cur ^= 1;
  }
#pragma unroll
  for (int m = 0; m < 4; ++m)
#pragma unroll
    for (int n = 0; n < 4; ++n)
#pragma unroll
      for (int j = 0; j < 4; ++j) {
        const int row = m0 + wr*64 + m*16 + g*4 + j;
        const int col = n0 + wc*64 + n*16 + l15;
        if constexpr (OBF16) ((u16*)Cv)[(size_t)row * N + col] = f2bf(acc[m][n][j]);
        else                 ((float*)Cv)[(size_t)row * N + col] = acc[m][n][j];
      }
}

// ---------------- RoPE + rank-contract + RMSNorm -> q,k,v (bf16) ----------------
__global__ __launch_bounds__(256)
void k_qkv(const u16* __restrict__ Y, const float* __restrict__ cosT,
           const float* __restrict__ sinT, const float* __restrict__ qw,
           const float* __restrict__ kw, u16* __restrict__ q_s,
           u16* __restrict__ k_s, u16* __restrict__ v_s) {
  const int s = blockIdx.x;
  const int d = threadIdx.x;
  __shared__ float row[NPROJ];
  __shared__ float red[12][4];
  const u16* yr = Y + (size_t)s * NPROJP;
  for (int u4 = d; u4 < NPROJ/4; u4 += 256) {
    ushort4 v4 = ((const ushort4*)yr)[u4];
    row[u4*4+0] = bf2f(v4.x); row[u4*4+1] = bf2f(v4.y);
    row[u4*4+2] = bf2f(v4.z); row[u4*4+3] = bf2f(v4.w);
  }
  __syncthreads();
  const int i = d >> 1;
  const float cf = cosT[s * 128 + i];
  const float sf = sinT[s * 128 + i];
  const bool odd = d & 1;
  float bq[6], bk[2], bv[2];
#pragma unroll
  for (int r = 0; r < 6; ++r) {
    float x1 = row[64 + r*256 + 2*i], x2 = row[64 + r*256 + 2*i + 1];
    bq[r] = odd ? (x1*sf + x2*cf) : (x1*cf - x2*sf);
  }
#pragma unroll
  for (int r = 0; r < 2; ++r) {
    float x1 = row[1600 + r*256 + 2*i], x2 = row[1600 + r*256 + 2*i + 1];
    bk[r] = odd ? (x1*sf + x2*cf) : (x1*cf - x2*sf);
    bv[r] = row[2112 + r*256 + d];
  }
  float qv[8], kv[4], vv[4];
#pragma unroll
  for (int h = 0; h < 8; ++h) {
    float a = 0.f;
#pragma unroll
    for (int r = 0; r < 6; ++r) a += row[h*6 + r] * bq[r];
    qv[h] = a * (1.0f / 6.0f);
  }
#pragma unroll
  for (int c = 0; c < 4; ++c) {
    kv[c] = (row[48 + c*2]*bk[0] + row[48 + c*2 + 1]*bk[1]) * 0.5f;
    vv[c] = (row[56 + c*2]*bv[0] + row[56 + c*2 + 1]*bv[1]) * 0.5f;
  }
  const int lane = d & 63, wv = d >> 6;
#pragma unroll
  for (int t = 0; t < 12; ++t) {
    float x = (t < 8) ? qv[t] : kv[t - 8];
    float ss = x * x;
#pragma unroll
    for (int off = 32; off > 0; off >>= 1) ss += __shfl_xor(ss, off);
    if (lane == 0) red[t][wv] = ss;
  }
  __syncthreads();
  const float qwf = 1.0f + qw[d], kwf = 1.0f + kw[d];
#pragma unroll
  for (int h = 0; h < 8; ++h) {
    float v = red[h][0] + red[h][1] + red[h][2] + red[h][3];
    float r = rsqrtf(v * (1.0f/256.0f) + 1e-6f);
    q_s[((size_t)s*8 + h)*256 + d] = f2bf(qv[h] * r * qwf * 0.0625f);  // fold SCALING
  }
#pragma unroll
  for (int c = 0; c < 4; ++c) {
    float v = red[8+c][0] + red[8+c][1] + red[8+c][2] + red[8+c][3];
    float r = rsqrtf(v * (1.0f/256.0f) + 1e-6f);
    k_s[((size_t)s*4 + c)*256 + d] = f2bf(kv[c] * r * kwf);
    v_s[((size_t)s*4 + c)*256 + d] = f2bf(vv[c]);
  }
}

// ---------------- v (s,c,d) -> vT (c,d,s) 64x64 tile transpose ----------------
__global__ __launch_bounds__(256)
void k_vt(const u16* __restrict__ v_s, u16* __restrict__ vT) {
  __shared__ u16 tile[64][72];
  const int s0 = blockIdx.x * 64, d0 = blockIdx.y * 64, c = blockIdx.z;
  const int tid = threadIdx.x;
#pragma unroll
  for (int it = 0; it < 2; ++it) {
    const int u = it * 256 + tid;
    const int r = u >> 3, cc = u & 7;
    const u16* s = &v_s[(((size_t)(s0 + r))*4 + c)*256 + d0 + cc*8];
    ushort4 a = *(const ushort4*)s, b = *(const ushort4*)(s + 4);
    tile[r][cc*8+0]=a.x; tile[r][cc*8+1]=a.y; tile[r][cc*8+2]=a.z; tile[r][cc*8+3]=a.w;
    tile[r][cc*8+4]=b.x; tile[r][cc*8+5]=b.y; tile[r][cc*8+6]=b.z; tile[r][cc*8+7]=b.w;
  }
  __syncthreads();
#pragma unroll
  for (int it = 0; it < 2; ++it) {
    const int u = it * 256 + tid;
    const int dr = u >> 3, sc = u & 7;
    ushort4 a, b;
    a.x = tile[sc*8+0][dr]; a.y = tile[sc*8+1][dr]; a.z = tile[sc*8+2][dr]; a.w = tile[sc*8+3][dr];
    b.x = tile[sc*8+4][dr]; b.y = tile[sc*8+5][dr]; b.z = tile[sc*8+6][dr]; b.w = tile[sc*8+7][dr];
    u16* o = vT + ((size_t)c*256 + d0 + dr)*SEQ + s0 + sc*8;
    *(ushort4*)o = a; *(ushort4*)(o + 4) = b;
  }
}

// -------- flash attention, round-split: 2 co-resident blocks/CU share a window --------
// Grid 512, b = sp*256 + qt*4 + c  -> co-resident pair (b, b+256) = same (qt,c).
// Block = 64 q x 2 heads, 8 waves (R6 decomposition), KVBLK=64, SINGLE-buffered
// K+V (64 KB -> 2 blocks/CU, 4 waves/SIMD). Block sp handles tiles kt = kt_lo+sp,
// +2, ... P stays in registers via mfma_16x16x16bf16_1k. Partials merged by k_mrg.
// Pre-stage barrier = sync_lgkm (rule #18) so single-buffer overwrite never races
// outstanding ds_reads.
__global__ __launch_bounds__(512, 4)
void k_attn(const u16* __restrict__ q_s, const u16* __restrict__ k_s,
            const u16* __restrict__ vT, const int* __restrict__ idx,
            u16* __restrict__ op, float2* __restrict__ ml) {
  __shared__ u16 Kt[64 * 256];   // 32 KB
  __shared__ u16 Vt[256 * 64];   // 32 KB
  const int b = blockIdx.x;
  const int c = b & 3, qt = (b >> 2) & 63, sp = b >> 8;
  const int q0 = qt * 64;
  const int tid = threadIdx.x;
  const int wid = tid >> 6, lane = tid & 63;
  const int l15 = lane & 15, g = lane >> 4;
  const int h = 2*c + (wid >> 2);             // waves 0-3 -> head 2c; 4-7 -> 2c+1
  const int qsub = wid & 3;
  const int qrow = q0 + qsub*16 + l15;
  const int qpos = idx[qrow];

  bf16x8 qf[8];
  const u16* qb = q_s + ((size_t)qrow * 8 + h) * 256;
#pragma unroll
  for (int kk = 0; kk < 8; ++kk) qf[kk] = *(const bf16x8*)(qb + kk*32 + g*8);

  const int sw = l15 & 7;
  int kbase[8];
#pragma unroll
  for (int kk = 0; kk < 8; ++kk)
    kbase[kk] = l15*256 + ((((kk<<2)+g) ^ sw) << 3);   // + nk*4096

  f32x4 accO[16];
#pragma unroll
  for (int n = 0; n < 16; ++n) accO[n] = (f32x4){0.f,0.f,0.f,0.f};
  float mrun = -50.0f, lrun = 0.0f;           // per-lane partial lrun

  int t0 = q0 - (WIN - 1); if (t0 < 0) t0 = 0;
  const int kt_lo = t0 >> 6, kt_hi = qt;
  const int kt0 = kt_lo + sp;                 // this block's first tile

  const u16* kgp = k_s + (size_t)(kt0*64 + (tid>>5)) * 1024 + c*256
                   + (((tid & 31) ^ ((tid >> 5) & 7)) << 3);
  const u16* vgp = vT + (size_t)c*1048576 + (size_t)(tid>>3)*4096 + kt0*64
                   + (((tid & 7) ^ ((tid >> 3) & 7)) << 3);

  auto stage = [&]() {
#pragma unroll
    for (int i = 0; i < 4; ++i)
      gl_lds16(kgp + i*16384,  &Kt[(i*512 + wid*64) * 8]);
#pragma unroll
    for (int i = 0; i < 4; ++i)
      gl_lds16(vgp + i*262144, &Vt[(i*512 + wid*64) * 8]);
  };

  if (kt0 <= kt_hi) stage();
  for (int kt = kt0; kt <= kt_hi; kt += 2) {
    const int k0 = kt << 6;
    sync_vm();                                 // this tile staged

    // S^T = K @ Q^T : D[key = nk*16 + g*4+j][q = l15]
    f32x4 sc[4];
#pragma unroll
    for (int nk = 0; nk < 4; ++nk) sc[nk] = (f32x4){0.f,0.f,0.f,0.f};
    __builtin_amdgcn_s_setprio(1);
#pragma unroll
    for (int nk = 0; nk < 4; ++nk)
#pragma unroll
      for (int kk = 0; kk < 8; ++kk) {
        bf16x8 kf = *(const bf16x8*)&Kt[nk*4096 + kbase[kk]];
        sc[nk] = __builtin_amdgcn_mfma_f32_16x16x32_bf16(kf, qf[kk], sc[nk], 0, 0, 0);
      }
    __builtin_amdgcn_s_setprio(0);

    // softcap: t = 50 - 100/(1+exp2(x*2*log2e/50))
    float tv[16];
#pragma unroll
    for (int nk = 0; nk < 4; ++nk)
#pragma unroll
      for (int j = 0; j < 4; ++j) {
        float u = __builtin_amdgcn_exp2f(sc[nk][j] * 0.05770780163555854f);
        tv[nk*4+j] = fmaf(-100.0f, __builtin_amdgcn_rcpf(1.0f + u), 50.0f);
      }
    if (kt == kt_hi) {                        // causal edge tile
#pragma unroll
      for (int nk = 0; nk < 4; ++nk)
#pragma unroll
        for (int j = 0; j < 4; ++j)
          if (k0 + nk*16 + g*4 + j > qpos) tv[nk*4+j] = -1e38f;
    } else if (kt == kt_lo) {                 // window edge tile
#pragma unroll
      for (int nk = 0; nk < 4; ++nk)
#pragma unroll
        for (int j = 0; j < 4; ++j)
          if (qpos - (k0 + nk*16 + g*4 + j) > 1023) tv[nk*4+j] = -1e38f;
    }

    float tmax = tv[0];
#pragma unroll
    for (int t = 1; t < 16; ++t) tmax = fmaxf(tmax, tv[t]);
    if (__any(tmax > mrun + 8.0f)) {          // defer-max: reduce only on trigger
      float tq = fmaxf(tmax, __shfl_xor(tmax, 16));
      tq = fmaxf(tq, __shfl_xor(tq, 32));
      const float mnew = fmaxf(mrun, tq);
      const float scale = __builtin_amdgcn_exp2f((mrun - mnew) * 1.442695041f);
      float scj[4];
#pragma unroll
      for (int j = 0; j < 4; ++j) scj[j] = __shfl(scale, g*4 + j);
#pragma unroll
      for (int n = 0; n < 16; ++n) {
        accO[n][0] *= scj[0]; accO[n][1] *= scj[1];
        accO[n][2] *= scj[2]; accO[n][3] *= scj[3];
      }
      lrun *= scale;
      mrun = mnew;
    }
    const float mr2 = mrun * 1.442695041f;
    float p[16];
#pragma unroll
    for (int t = 0; t < 16; ++t) {
      p[t] = __builtin_amdgcn_exp2f(fmaf(tv[t], 1.442695041f, -mr2));
      lrun += p[t];
    }

    // O += P @ V in registers: A-frag(16x16x16) [q=l15][k=g*4+i] == our p layout
    __builtin_amdgcn_s_setprio(1);
#pragma unroll
    for (int nk = 0; nk < 4; ++nk) {
      union { uint32_t u[2]; bf16x4 v; } pu;
      pu.u[0] = cvtpk(p[nk*4+0], p[nk*4+1]);
      pu.u[1] = cvtpk(p[nk*4+2], p[nk*4+3]);
#pragma unroll
      for (int n = 0; n < 16; ++n) {
        const int dr = n*16 + l15;
        bf16x4 vf = *(const bf16x4*)&Vt[dr*64 + (((2*nk + (g>>1)) ^ sw) << 3) + (g&1)*4];
        accO[n] = __builtin_amdgcn_mfma_f32_16x16x16bf16_1k(pu.v, vf, accO[n], 0, 0, 0);
      }
    }
    __builtin_amdgcn_s_setprio(0);

    sync_lgkm();                               // ALL LDS reads drained before overwrite
    if (kt + 2 <= kt_hi) { kgp += 131072; vgp += 128; stage(); }
  }

  lrun += __shfl_xor(lrun, 16);
  lrun += __shfl_xor(lrun, 32);
  if (g == 0) ml[(size_t)sp*SEQ*NHEAD + (size_t)qrow*NHEAD + h] = make_float2(mrun, lrun);
  u16* opS = op + (size_t)sp*SEQ*HIDN;
#pragma unroll
  for (int n = 0; n < 16; ++n)
#pragma unroll
    for (int j = 0; j < 4; ++j) {
      const int r = q0 + qsub*16 + g*4 + j;
      opS[(size_t)r * HIDN + h*256 + n*16 + l15] = f2bf(accO[n][j]);
    }
}

// ---------------- merge the two round-split partials (log-sum-exp) ----------------
__global__ __launch_bounds__(256)
void k_mrg(const u16* __restrict__ op, const float2* __restrict__ ml,
           u16* __restrict__ ao) {
  const int q = blockIdx.x;
  const int h = threadIdx.x >> 5;
  const int dd = (threadIdx.x & 31) * 8;
  const float2 a = ml[(size_t)q*NHEAD + h];
  const float2 b = ml[(size_t)SEQ*NHEAD + (size_t)q*NHEAD + h];
  const float M = fmaxf(a.x, b.x);
  float w0 = __builtin_amdgcn_exp2f((a.x - M) * 1.442695041f);
  float w1 = __builtin_amdgcn_exp2f((b.x - M) * 1.442695041f);
  const float r = __builtin_amdgcn_rcpf(w0 * a.y + w1 * b.y);
  w0 *= r; w1 *= r;
  const size_t base = (size_t)q * HIDN + h*256 + dd;
  bf16x8 o0 = *(const bf16x8*)&op[base];
  bf16x8 o1 = *(const bf16x8*)&op[(size_t)SEQ*HIDN + base];
  ushort4 lo, hi;
  u16 ov[8];
#pragma unroll
  for (int j = 0; j < 8; ++j)
    ov[j] = f2bf(w0 * bf2f((u16)o0[j]) + w1 * bf2f((u16)o1[j]));
  lo.x = ov[0]; lo.y = ov[1]; lo.z = ov[2]; lo.w = ov[3];
  hi.x = ov[4]; hi.y = ov[5]; hi.z = ov[6]; hi.w = ov[7];
  *(ushort4*)&ao[base] = lo;
  *(ushort4*)&ao[base + 4] = hi;
}

// ---------------- launch ----------------
extern "C" void kernel_launch(void* const* d_in, const int* in_sizes, int n_in,
                              void* d_out, int out_size, void* d_ws, size_t ws_size,
                              hipStream_t stream) {
  const float* x    = (const float*)d_in[0];
  const float* fcos = (const float*)d_in[1];
  const float* fsin = (const float*)d_in[2];
  const float* waq  = (const float*)d_in[3];
  const float* wak  = (const float*)d_in[4];
  const float* wav  = (const float*)d_in[5];
  const float* wbq  = (const float*)d_in[6];
  const float* wbk  = (const float*)d_in[7];
  const float* wbv  = (const float*)d_in[8];
  const float* wo   = (const float*)d_in[9];
  const float* qnw  = (const float*)d_in[10];
  const float* knw  = (const float*)d_in[11];
  const int*   idx  = (const int*)d_in[16];
  float* out = (float*)d_out;

  char* p = (char*)d_ws;
  u16*  xb   = (u16*)p;                 p += (size_t)SEQ*HIDN*2;
  u16*  wcat = (u16*)p;                 p += (size_t)NPROJP*HIDN*2;
  u16*  wob  = (u16*)p;                 p += (size_t)HIDN*HIDN*2;
  u16*  ypr  = (u16*)p;                 p += (size_t)SEQ*NPROJP*2;     // proj out bf16
  u16*  q_s  = (u16*)p;                 p += (size_t)SEQ*NHEAD*DH*2;
  u16*  k_s  = (u16*)p;                 p += (size_t)SEQ*NKVH*DH*2;
  u16*  v_s  = (u16*)p;                 p += (size_t)SEQ*NKVH*DH*2;
  u16*  vT   = (u16*)p;                 p += (size_t)SEQ*NKVH*DH*2;
  u16*  ao   = (u16*)p;                 p += (size_t)SEQ*HIDN*2;
  u16*  op   = (u16*)p;                 p += (size_t)2*SEQ*HIDN*2;     // split partials
  float2* ml = (float2*)p;              p += (size_t)2*SEQ*NHEAD*sizeof(float2);

  k_cvt <<<(SEQ*HIDN/4 + 255)/256, 256, 0, stream>>>(x, xb, SEQ*HIDN/4);
  k_cvt <<<(HIDN*HIDN/4 + 255)/256, 256, 0, stream>>>(wo, wob, HIDN*HIDN/4);
  k_wcat<<<NPROJP, 256, 0, stream>>>(waq, wak, wav, wbq, wbk, wbv, wcat);
  k_gemm_bt<1><<<dim3(NPROJP/128, SEQ/128), 256, 0, stream>>>(xb, wcat, ypr, SEQ, NPROJP, HIDN);
  k_qkv <<<SEQ, 256, 0, stream>>>(ypr, fcos, fsin, qnw, knw, q_s, k_s, v_s);
  k_vt  <<<dim3(SEQ/64, DH/64, NKVH), 256, 0, stream>>>(v_s, vT);
  k_attn<<<dim3(2 * SEQ/64 * NKVH), 512, 0, stream>>>(q_s, k_s, vT, idx, op, ml);
  k_mrg <<<SEQ, 256, 0, stream>>>(op, ml, ao);
  k_gemm_bt<0><<<dim3(HIDN/128, SEQ/128), 256, 0, stream>>>(ao, wob, out, SEQ, HIDN, HIDN);
}

// Round 13
// 214.730 us; speedup vs baseline: 1.4003x; 1.4003x over previous
//
#include <hip/hip_runtime.h>
#include <hip/hip_bf16.h>
#include <cstdint>
#include <cstddef>

// ---- problem constants ----
constexpr int SEQ   = 4096;
constexpr int HIDN  = 2048;
constexpr int NHEAD = 8;
constexpr int NKVH  = 4;
constexpr int DH    = 256;
constexpr int NPROJ = 2624;      // 48 + 8 + 8 + 1536 + 512 + 512
constexpr int NPROJP= 2688;      // padded to /128
constexpr int WIN   = 1024;

typedef __attribute__((ext_vector_type(4))) float f32x4;
typedef __attribute__((ext_vector_type(8))) short bf16x8;
typedef unsigned short u16;

__device__ __forceinline__ u16 f2bf(float x) {
  union { float f; uint32_t u; } v; v.f = x;
  uint32_t r = v.u + 0x7fffu + ((v.u >> 16) & 1u);
  return (u16)(r >> 16);
}
__device__ __forceinline__ float bf2f(u16 v) {
  union { uint32_t u; float f; } w; w.u = (uint32_t)v << 16; return w.f;
}

__device__ __forceinline__ uint32_t cvtpk(float lo, float hi) {
  uint32_t r;
  asm("v_cvt_pk_bf16_f32 %0, %1, %2" : "=v"(r) : "v"(lo), "v"(hi));
  return r;
}

// async global->LDS, 16B per lane, dest = wave-uniform base + lane*16 (linear)
__device__ __forceinline__ void gl_lds16(const u16* g, u16* l) {
  __builtin_amdgcn_global_load_lds(
      (const __attribute__((address_space(1))) uint32_t*)g,
      (__attribute__((address_space(3))) uint32_t*)l, 16, 0, 0);
}

// barrier draining only VMEM (staged gl_lds); nothing else pinned
__device__ __forceinline__ void sync_vm() {
  asm volatile("s_waitcnt vmcnt(0)" ::: "memory");
  __builtin_amdgcn_s_barrier();
  __builtin_amdgcn_sched_barrier(0);
}

// bijective XCD-aware workgroup remap (m204)
__device__ __forceinline__ int xcd_swz(int wg, int nwg) {
  const int q = nwg >> 3, r = nwg & 7;
  const int xcd = wg & 7, lo = wg >> 3;
  return (xcd < r ? xcd * (q + 1) : r * (q + 1) + (xcd - r) * q) + lo;
}

// ---------------- fused prep: cvt(x) + cvt(wo) + wcat in one dispatch ----------------
// blocks [0,8192)      : x f32 -> bf16      (8192*256 float4 == SEQ*HIDN/4 exactly)
// blocks [8192,12288)  : wo f32 -> bf16     (4096*256 float4 == HIDN*HIDN/4 exactly)
// blocks [12288,14976) : wcat row build     (2688 rows)
__global__ __launch_bounds__(256)
void k_prep(const float* __restrict__ x,  u16* __restrict__ xb,
            const float* __restrict__ wo, u16* __restrict__ wob,
            const float* __restrict__ waq, const float* __restrict__ wak,
            const float* __restrict__ wav, const float* __restrict__ wbq,
            const float* __restrict__ wbk, const float* __restrict__ wbv,
            u16* __restrict__ wcat) {
  const int bid = blockIdx.x;
  if (bid < 12288) {
    const float* src = (bid < 8192) ? x  : wo;
    u16*        dst  = (bid < 8192) ? xb : wob;
    const int   i    = (bid < 8192 ? bid : bid - 8192) * 256 + threadIdx.x;
    float4 v = ((const float4*)src)[i];
    ushort4 o; o.x = f2bf(v.x); o.y = f2bf(v.y); o.z = f2bf(v.z); o.w = f2bf(v.w);
    ((ushort4*)dst)[i] = o;
    return;
  }
  const int r = bid - 12288;           // 0..2687
  const int col0 = threadIdx.x * 8;
  u16* out = wcat + (size_t)r * HIDN + col0;
  const float* src = nullptr; int rr = 0;
  if      (r < 48)   { src = waq; rr = r; }
  else if (r < 56)   { src = wak; rr = r - 48; }
  else if (r < 64)   { src = wav; rr = r - 56; }
  else if (r < 1600) { src = wbq; rr = r - 64; }
  else if (r < 2112) { src = wbk; rr = r - 1600; }
  else if (r < 2624) { src = wbv; rr = r - 2112; }
  if (!src) {
    ushort4 z = {0,0,0,0}; ((ushort4*)out)[0] = z; ((ushort4*)out)[1] = z; return;
  }
  const float* s = src + (size_t)rr * HIDN + col0;
#pragma unroll
  for (int i = 0; i < 2; ++i) {
    float4 v = ((const float4*)s)[i];
    ushort4 o; o.x = f2bf(v.x); o.y = f2bf(v.y); o.z = f2bf(v.z); o.w = f2bf(v.w);
    ((ushort4*)out)[i] = o;
  }
}

// ---------------- bf16 GEMM: C(MxN) = A(MxK) @ B(NxK)^T (R4/R6 best) ----------------
template<int OBF16>
__global__ __launch_bounds__(256)
void k_gemm_bt(const u16* __restrict__ A, const u16* __restrict__ Bm,
               void* __restrict__ Cv, int M, int N, int K) {
  __shared__ u16 lA[2][128 * 32];
  __shared__ u16 lB[2][128 * 32];
  const int tid = threadIdx.x;
  const int wid = tid >> 6, lane = tid & 63;
  const int l15 = lane & 15, g = lane >> 4;
  const int nwg = gridDim.x * gridDim.y;
  int wg = xcd_swz(blockIdx.y * gridDim.x + blockIdx.x, nwg);
  const int m0 = (wg / gridDim.x) * 128, n0 = (wg % gridDim.x) * 128;
  const int wr = wid >> 1, wc = wid & 1;
  f32x4 acc[4][4];
#pragma unroll
  for (int m = 0; m < 4; ++m)
#pragma unroll
    for (int n = 0; n < 4; ++n) acc[m][n] = (f32x4){0.f,0.f,0.f,0.f};
  const int NT = K >> 5;

  auto stage = [&](int buf, int kt) {
    const int k0 = kt << 5;
#pragma unroll
    for (int i = 0; i < 2; ++i) {
      const int u = i * 256 + tid;
      const int row = u >> 2, cs = u & 3;
      const int cc = cs ^ ((row >> 1) & 3);
      gl_lds16(A  + (size_t)(m0 + row) * K + k0 + cc * 8, &lA[buf][(i*256 + wid*64) * 8]);
      gl_lds16(Bm + (size_t)(n0 + row) * K + k0 + cc * 8, &lB[buf][(i*256 + wid*64) * 8]);
    }
  };

  stage(0, 0);
  int cur = 0;
  for (int kt = 0; kt < NT; ++kt) {
    __syncthreads();
    if (kt + 1 < NT) stage(cur ^ 1, kt + 1);
    bf16x8 af[4], bfr[4];
#pragma unroll
    for (int m = 0; m < 4; ++m) {
      const int row = wr*64 + m*16 + l15;
      const int cc = g ^ ((row >> 1) & 3);
      af[m] = *(const bf16x8*)&lA[cur][row*32 + cc*8];
    }
#pragma unroll
    for (int n = 0; n < 4; ++n) {
      const int row = wc*64 + n*16 + l15;
      const int cc = g ^ ((row >> 1) & 3);
      bfr[n] = *(const bf16x8*)&lB[cur][row*32 + cc*8];
    }
    __builtin_amdgcn_s_setprio(1);
#pragma unroll
    for (int m = 0; m < 4; ++m)
#pragma unroll
      for (int n = 0; n < 4; ++n)
        acc[m][n] = __builtin_amdgcn_mfma_f32_16x16x32_bf16(af[m], bfr[n], acc[m][n], 0, 0, 0);
    __builtin_amdgcn_s_setprio(0);
    cur ^= 1;
  }
#pragma unroll
  for (int m = 0; m < 4; ++m)
#pragma unroll
    for (int n = 0; n < 4; ++n)
#pragma unroll
      for (int j = 0; j < 4; ++j) {
        const int row = m0 + wr*64 + m*16 + g*4 + j;
        const int col = n0 + wc*64 + n*16 + l15;
        if constexpr (OBF16) ((u16*)Cv)[(size_t)row * N + col] = f2bf(acc[m][n][j]);
        else                 ((float*)Cv)[(size_t)row * N + col] = acc[m][n][j];
      }
}

// ---------------- RoPE + rank-contract + RMSNorm -> q,k,v (bf16) ----------------
__global__ __launch_bounds__(256)
void k_qkv(const u16* __restrict__ Y, const float* __restrict__ cosT,
           const float* __restrict__ sinT, const float* __restrict__ qw,
           const float* __restrict__ kw, u16* __restrict__ q_s,
           u16* __restrict__ k_s, u16* __restrict__ v_s) {
  const int s = blockIdx.x;
  const int d = threadIdx.x;
  __shared__ float row[NPROJ];
  __shared__ float red[12][4];
  const u16* yr = Y + (size_t)s * NPROJP;
  for (int u4 = d; u4 < NPROJ/4; u4 += 256) {
    ushort4 v4 = ((const ushort4*)yr)[u4];
    row[u4*4+0] = bf2f(v4.x); row[u4*4+1] = bf2f(v4.y);
    row[u4*4+2] = bf2f(v4.z); row[u4*4+3] = bf2f(v4.w);
  }
  __syncthreads();
  const int i = d >> 1;
  const float cf = cosT[s * 128 + i];
  const float sf = sinT[s * 128 + i];
  const bool odd = d & 1;
  float bq[6], bk[2], bv[2];
#pragma unroll
  for (int r = 0; r < 6; ++r) {
    float x1 = row[64 + r*256 + 2*i], x2 = row[64 + r*256 + 2*i + 1];
    bq[r] = odd ? (x1*sf + x2*cf) : (x1*cf - x2*sf);
  }
#pragma unroll
  for (int r = 0; r < 2; ++r) {
    float x1 = row[1600 + r*256 + 2*i], x2 = row[1600 + r*256 + 2*i + 1];
    bk[r] = odd ? (x1*sf + x2*cf) : (x1*cf - x2*sf);
    bv[r] = row[2112 + r*256 + d];
  }
  float qv[8], kv[4], vv[4];
#pragma unroll
  for (int h = 0; h < 8; ++h) {
    float a = 0.f;
#pragma unroll
    for (int r = 0; r < 6; ++r) a += row[h*6 + r] * bq[r];
    qv[h] = a * (1.0f / 6.0f);
  }
#pragma unroll
  for (int c = 0; c < 4; ++c) {
    kv[c] = (row[48 + c*2]*bk[0] + row[48 + c*2 + 1]*bk[1]) * 0.5f;
    vv[c] = (row[56 + c*2]*bv[0] + row[56 + c*2 + 1]*bv[1]) * 0.5f;
  }
  const int lane = d & 63, wv = d >> 6;
#pragma unroll
  for (int t = 0; t < 12; ++t) {
    float x = (t < 8) ? qv[t] : kv[t - 8];
    float ss = x * x;
#pragma unroll
    for (int off = 32; off > 0; off >>= 1) ss += __shfl_xor(ss, off);
    if (lane == 0) red[t][wv] = ss;
  }
  __syncthreads();
  const float qwf = 1.0f + qw[d], kwf = 1.0f + kw[d];
#pragma unroll
  for (int h = 0; h < 8; ++h) {
    float v = red[h][0] + red[h][1] + red[h][2] + red[h][3];
    float r = rsqrtf(v * (1.0f/256.0f) + 1e-6f);
    q_s[((size_t)s*8 + h)*256 + d] = f2bf(qv[h] * r * qwf * 0.0625f);  // fold SCALING
  }
#pragma unroll
  for (int c = 0; c < 4; ++c) {
    float v = red[8+c][0] + red[8+c][1] + red[8+c][2] + red[8+c][3];
    float r = rsqrtf(v * (1.0f/256.0f) + 1e-6f);
    k_s[((size_t)s*4 + c)*256 + d] = f2bf(kv[c] * r * kwf);
    v_s[((size_t)s*4 + c)*256 + d] = f2bf(vv[c]);
  }
}

// ---------------- v (s,c,d) -> vT (c,d,s) 64x64 tile transpose ----------------
__global__ __launch_bounds__(256)
void k_vt(const u16* __restrict__ v_s, u16* __restrict__ vT) {
  __shared__ u16 tile[64][72];
  const int s0 = blockIdx.x * 64, d0 = blockIdx.y * 64, c = blockIdx.z;
  const int tid = threadIdx.x;
#pragma unroll
  for (int it = 0; it < 2; ++it) {
    const int u = it * 256 + tid;
    const int r = u >> 3, cc = u & 7;
    const u16* s = &v_s[(((size_t)(s0 + r))*4 + c)*256 + d0 + cc*8];
    ushort4 a = *(const ushort4*)s, b = *(const ushort4*)(s + 4);
    tile[r][cc*8+0]=a.x; tile[r][cc*8+1]=a.y; tile[r][cc*8+2]=a.z; tile[r][cc*8+3]=a.w;
    tile[r][cc*8+4]=b.x; tile[r][cc*8+5]=b.y; tile[r][cc*8+6]=b.z; tile[r][cc*8+7]=b.w;
  }
  __syncthreads();
#pragma unroll
  for (int it = 0; it < 2; ++it) {
    const int u = it * 256 + tid;
    const int dr = u >> 3, sc = u & 7;
    ushort4 a, b;
    a.x = tile[sc*8+0][dr]; a.y = tile[sc*8+1][dr]; a.z = tile[sc*8+2][dr]; a.w = tile[sc*8+3][dr];
    b.x = tile[sc*8+4][dr]; b.y = tile[sc*8+5][dr]; b.z = tile[sc*8+6][dr]; b.w = tile[sc*8+7][dr];
    u16* o = vT + ((size_t)c*256 + d0 + dr)*SEQ + s0 + sc*8;
    *(ushort4*)o = a; *(ushort4*)(o + 4) = b;
  }
}

// ---------------- flash attention (R6 structure, best measured: 69 us) ----------------
// ONE 512-thread block per CU: 64 queries x 2 heads (GQA pair shares K/V),
// 8 waves (wid>>2 = head, wid&3 = 16-query subtile). KVBLK=64, dbuf K+V,
// one vmcnt(0)+s_barrier per 64-key round. LDS 145 KB (1 block/CU).
__global__ __launch_bounds__(512, 2)
void k_attn(const u16* __restrict__ q_s, const u16* __restrict__ k_s,
            const u16* __restrict__ vT, const int* __restrict__ idx,
            u16* __restrict__ ao) {
  __shared__ u16 Kt[2][64 * 256];   // 32 KB x2
  __shared__ u16 Vt[2][256 * 64];   // 32 KB x2
  __shared__ u16 Pb[8][16 * 68];    // 17 KB wave-private P (16q x 64k, pad 4)
  const int b = blockIdx.x;
  const int c = b & 3, qt = b >> 2;           // c -> XCD affinity
  const int q0 = qt * 64;
  const int tid = threadIdx.x;
  const int wid = tid >> 6, lane = tid & 63;
  const int l15 = lane & 15, g = lane >> 4;
  const int h = 2*c + (wid >> 2);             // waves 0-3 -> head 2c; 4-7 -> 2c+1
  const int qsub = wid & 3;
  const int qrow = q0 + qsub*16 + l15;
  const int qpos = idx[qrow];

  bf16x8 qf[8];
  const u16* qb = q_s + ((size_t)qrow * 8 + h) * 256;
#pragma unroll
  for (int kk = 0; kk < 8; ++kk) qf[kk] = *(const bf16x8*)(qb + kk*32 + g*8);

  const int sw = l15 & 7;
  int kbase[8];
#pragma unroll
  for (int kk = 0; kk < 8; ++kk)
    kbase[kk] = l15*256 + ((((kk<<2)+g) ^ sw) << 3);   // + nk*4096 + kco
  u16* KtF = &Kt[0][0];
  u16* VtF = &Vt[0][0];
  u16* Pw  = &Pb[wid][0];

  f32x4 accO[16];
#pragma unroll
  for (int n = 0; n < 16; ++n) accO[n] = (f32x4){0.f,0.f,0.f,0.f};
  float mrun = -50.0f, lrun = 0.0f;           // per-lane partial lrun

  int t0 = q0 - (WIN - 1); if (t0 < 0) t0 = 0;
  const int kt_lo = t0 >> 6, kt_hi = qt;

  const u16* kgp = k_s + (size_t)(kt_lo*64 + (tid>>5)) * 1024 + c*256
                   + (((tid & 31) ^ ((tid >> 5) & 7)) << 3);
  const u16* vgp = vT + (size_t)c*1048576 + (size_t)(tid>>3)*4096 + kt_lo*64
                   + (((tid & 7) ^ ((tid >> 3) & 7)) << 3);

  auto stage = [&](int buf) {
#pragma unroll
    for (int i = 0; i < 4; ++i)
      gl_lds16(kgp + i*16384,  &Kt[buf][(i*512 + wid*64) * 8]);
#pragma unroll
    for (int i = 0; i < 4; ++i)
      gl_lds16(vgp + i*262144, &Vt[buf][(i*512 + wid*64) * 8]);
  };

  stage(0);
  int cur = 0;
  for (int kt = kt_lo; kt <= kt_hi; ++kt) {
    const int k0 = kt << 6;
    sync_vm();                                 // buf[cur] staged (issued 1 round ago)
    if (kt < kt_hi) { kgp += 65536; vgp += 64; stage(cur ^ 1); }

    // S^T = K @ Q^T : D[key = nk*16 + g*4+j][q = l15]
    const int kco = cur * 16384;
    f32x4 sc[4];
#pragma unroll
    for (int nk = 0; nk < 4; ++nk) sc[nk] = (f32x4){0.f,0.f,0.f,0.f};
    __builtin_amdgcn_s_setprio(1);
#pragma unroll
    for (int nk = 0; nk < 4; ++nk)
#pragma unroll
      for (int kk = 0; kk < 8; ++kk) {
        bf16x8 kf = *(const bf16x8*)&KtF[kco + nk*4096 + kbase[kk]];
        sc[nk] = __builtin_amdgcn_mfma_f32_16x16x32_bf16(kf, qf[kk], sc[nk], 0, 0, 0);
      }
    __builtin_amdgcn_s_setprio(0);

    // softcap: t = 50 - 100/(1+exp2(x*2*log2e/50))
    float tv[16];
#pragma unroll
    for (int nk = 0; nk < 4; ++nk)
#pragma unroll
      for (int j = 0; j < 4; ++j) {
        float u = __builtin_amdgcn_exp2f(sc[nk][j] * 0.05770780163555854f);
        tv[nk*4+j] = fmaf(-100.0f, __builtin_amdgcn_rcpf(1.0f + u), 50.0f);
      }
    if (kt == kt_hi) {                        // causal edge tile
#pragma unroll
      for (int nk = 0; nk < 4; ++nk)
#pragma unroll
        for (int j = 0; j < 4; ++j)
          if (k0 + nk*16 + g*4 + j > qpos) tv[nk*4+j] = -1e38f;
    } else if (kt == kt_lo) {                 // window edge tile
#pragma unroll
      for (int nk = 0; nk < 4; ++nk)
#pragma unroll
        for (int j = 0; j < 4; ++j)
          if (qpos - (k0 + nk*16 + g*4 + j) > 1023) tv[nk*4+j] = -1e38f;
    }

    float tmax = tv[0];
#pragma unroll
    for (int t = 1; t < 16; ++t) tmax = fmaxf(tmax, tv[t]);
    if (__any(tmax > mrun + 8.0f)) {          // defer-max: reduce only on trigger
      float tq = fmaxf(tmax, __shfl_xor(tmax, 16));
      tq = fmaxf(tq, __shfl_xor(tq, 32));
      const float mnew = fmaxf(mrun, tq);
      const float scale = __builtin_amdgcn_exp2f((mrun - mnew) * 1.442695041f);
      float scj[4];
#pragma unroll
      for (int j = 0; j < 4; ++j) scj[j] = __shfl(scale, g*4 + j);
#pragma unroll
      for (int n = 0; n < 16; ++n) {
        accO[n][0] *= scj[0]; accO[n][1] *= scj[1];
        accO[n][2] *= scj[2]; accO[n][3] *= scj[3];
      }
      lrun *= scale;
      mrun = mnew;
    }
    const float mr2 = mrun * 1.442695041f;
    float p[16];
#pragma unroll
    for (int t = 0; t < 16; ++t) {
      p[t] = __builtin_amdgcn_exp2f(fmaf(tv[t], 1.442695041f, -mr2));
      lrun += p[t];
    }

    // P -> wave-private LDS (bf16): key position nk*16+g*4..+3 of row l15
#pragma unroll
    for (int nk = 0; nk < 4; ++nk) {
      uint2 w = { cvtpk(p[nk*4+0], p[nk*4+1]), cvtpk(p[nk*4+2], p[nk*4+3]) };
      *(uint2*)&Pw[l15*68 + nk*16 + g*4] = w;
    }
    // O += P @ V : A-frag P[q=l15][k=half*32+g*8..], B-frag V^T[d=n*16+l15][k]
    const int vco = cur * 16384;
    __builtin_amdgcn_s_setprio(1);
#pragma unroll
    for (int half = 0; half < 2; ++half) {
      bf16x8 pa = *(const bf16x8*)&Pw[l15*68 + half*32 + g*8];
#pragma unroll
      for (int n = 0; n < 16; ++n) {
        bf16x8 vf = *(const bf16x8*)&VtF[vco + (n*16 + l15)*64
                                         + ((((half<<2)+g) ^ sw) << 3)];
        accO[n] = __builtin_amdgcn_mfma_f32_16x16x32_bf16(pa, vf, accO[n], 0, 0, 0);
      }
    }
    __builtin_amdgcn_s_setprio(0);
    cur ^= 1;
  }

  lrun += __shfl_xor(lrun, 16);
  lrun += __shfl_xor(lrun, 32);
  const float linv = __builtin_amdgcn_rcpf(lrun);
  float lj[4];
#pragma unroll
  for (int j = 0; j < 4; ++j) lj[j] = __shfl(linv, g*4 + j);
#pragma unroll
  for (int n = 0; n < 16; ++n)
#pragma unroll
    for (int j = 0; j < 4; ++j) {
      const int r = q0 + qsub*16 + g*4 + j;
      ao[(size_t)r * HIDN + h*256 + n*16 + l15] = f2bf(accO[n][j] * lj[j]);
    }
}

// ---------------- launch ----------------
extern "C" void kernel_launch(void* const* d_in, const int* in_sizes, int n_in,
                              void* d_out, int out_size, void* d_ws, size_t ws_size,
                              hipStream_t stream) {
  const float* x    = (const float*)d_in[0];
  const float* fcos = (const float*)d_in[1];
  const float* fsin = (const float*)d_in[2];
  const float* waq  = (const float*)d_in[3];
  const float* wak  = (const float*)d_in[4];
  const float* wav  = (const float*)d_in[5];
  const float* wbq  = (const float*)d_in[6];
  const float* wbk  = (const float*)d_in[7];
  const float* wbv  = (const float*)d_in[8];
  const float* wo   = (const float*)d_in[9];
  const float* qnw  = (const float*)d_in[10];
  const float* knw  = (const float*)d_in[11];
  const int*   idx  = (const int*)d_in[16];
  float* out = (float*)d_out;

  char* p = (char*)d_ws;
  u16*  xb   = (u16*)p;                 p += (size_t)SEQ*HIDN*2;
  u16*  wcat = (u16*)p;                 p += (size_t)NPROJP*HIDN*2;
  u16*  wob  = (u16*)p;                 p += (size_t)HIDN*HIDN*2;
  u16*  ypr  = (u16*)p;                 p += (size_t)SEQ*NPROJP*2;     // proj out bf16
  u16*  q_s  = (u16*)p;                 p += (size_t)SEQ*NHEAD*DH*2;
  u16*  k_s  = (u16*)p;                 p += (size_t)SEQ*NKVH*DH*2;
  u16*  v_s  = (u16*)p;                 p += (size_t)SEQ*NKVH*DH*2;
  u16*  vT   = (u16*)p;                 p += (size_t)SEQ*NKVH*DH*2;
  u16*  ao   = (u16*)p;                 p += (size_t)SEQ*HIDN*2;

  k_prep<<<14976, 256, 0, stream>>>(x, xb, wo, wob, waq, wak, wav, wbq, wbk, wbv, wcat);
  k_gemm_bt<1><<<dim3(NPROJP/128, SEQ/128), 256, 0, stream>>>(xb, wcat, ypr, SEQ, NPROJP, HIDN);
  k_qkv <<<SEQ, 256, 0, stream>>>(ypr, fcos, fsin, qnw, knw, q_s, k_s, v_s);
  k_vt  <<<dim3(SEQ/64, DH/64, NKVH), 256, 0, stream>>>(v_s, vT);
  k_attn<<<dim3(SEQ/64 * NKVH), 512, 0, stream>>>(q_s, k_s, vT, idx, ao);
  k_gemm_bt<0><<<dim3(HIDN/128, SEQ/128), 256, 0, stream>>>(ao, wob, out, SEQ, HIDN, HIDN);
}

// Round 14
// 213.715 us; speedup vs baseline: 1.4069x; 1.0047x over previous
//
#include <hip/hip_runtime.h>
#include <hip/hip_bf16.h>
#include <cstdint>
#include <cstddef>

// ---- problem constants ----
constexpr int SEQ   = 4096;
constexpr int HIDN  = 2048;
constexpr int NHEAD = 8;
constexpr int NKVH  = 4;
constexpr int DH    = 256;
constexpr int NPROJ = 2624;      // 48 + 8 + 8 + 1536 + 512 + 512
constexpr int NPROJP= 2688;      // padded to /128
constexpr int WIN   = 1024;

typedef __attribute__((ext_vector_type(4))) float f32x4;
typedef __attribute__((ext_vector_type(8))) short bf16x8;
typedef unsigned short u16;

__device__ __forceinline__ u16 f2bf(float x) {
  union { float f; uint32_t u; } v; v.f = x;
  uint32_t r = v.u + 0x7fffu + ((v.u >> 16) & 1u);
  return (u16)(r >> 16);
}
__device__ __forceinline__ float bf2f(u16 v) {
  union { uint32_t u; float f; } w; w.u = (uint32_t)v << 16; return w.f;
}

__device__ __forceinline__ uint32_t cvtpk(float lo, float hi) {
  uint32_t r;
  asm("v_cvt_pk_bf16_f32 %0, %1, %2" : "=v"(r) : "v"(lo), "v"(hi));
  return r;
}

// async global->LDS, 16B per lane, dest = wave-uniform base + lane*16 (linear)
__device__ __forceinline__ void gl_lds16(const u16* g, u16* l) {
  __builtin_amdgcn_global_load_lds(
      (const __attribute__((address_space(1))) uint32_t*)g,
      (__attribute__((address_space(3))) uint32_t*)l, 16, 0, 0);
}

// barrier draining only VMEM (staged gl_lds); nothing else pinned
__device__ __forceinline__ void sync_vm() {
  asm volatile("s_waitcnt vmcnt(0)" ::: "memory");
  __builtin_amdgcn_s_barrier();
  __builtin_amdgcn_sched_barrier(0);
}

// bijective XCD-aware workgroup remap (m204)
__device__ __forceinline__ int xcd_swz(int wg, int nwg) {
  const int q = nwg >> 3, r = nwg & 7;
  const int xcd = wg & 7, lo = wg >> 3;
  return (xcd < r ? xcd * (q + 1) : r * (q + 1) + (xcd - r) * q) + lo;
}

// ---------------- fused prep: cvt(x) + cvt(wo) + wcat in one dispatch ----------------
// blocks [0,8192)      : x f32 -> bf16      (8192*256 float4 == SEQ*HIDN/4 exactly)
// blocks [8192,12288)  : wo f32 -> bf16     (4096*256 float4 == HIDN*HIDN/4 exactly)
// blocks [12288,14976) : wcat row build     (2688 rows)
__global__ __launch_bounds__(256)
void k_prep(const float* __restrict__ x,  u16* __restrict__ xb,
            const float* __restrict__ wo, u16* __restrict__ wob,
            const float* __restrict__ waq, const float* __restrict__ wak,
            const float* __restrict__ wav, const float* __restrict__ wbq,
            const float* __restrict__ wbk, const float* __restrict__ wbv,
            u16* __restrict__ wcat) {
  const int bid = blockIdx.x;
  if (bid < 12288) {
    const float* src = (bid < 8192) ? x  : wo;
    u16*        dst  = (bid < 8192) ? xb : wob;
    const int   i    = (bid < 8192 ? bid : bid - 8192) * 256 + threadIdx.x;
    float4 v = ((const float4*)src)[i];
    ushort4 o; o.x = f2bf(v.x); o.y = f2bf(v.y); o.z = f2bf(v.z); o.w = f2bf(v.w);
    ((ushort4*)dst)[i] = o;
    return;
  }
  const int r = bid - 12288;           // 0..2687
  const int col0 = threadIdx.x * 8;
  u16* out = wcat + (size_t)r * HIDN + col0;
  const float* src = nullptr; int rr = 0;
  if      (r < 48)   { src = waq; rr = r; }
  else if (r < 56)   { src = wak; rr = r - 48; }
  else if (r < 64)   { src = wav; rr = r - 56; }
  else if (r < 1600) { src = wbq; rr = r - 64; }
  else if (r < 2112) { src = wbk; rr = r - 1600; }
  else if (r < 2624) { src = wbv; rr = r - 2112; }
  if (!src) {
    ushort4 z = {0,0,0,0}; ((ushort4*)out)[0] = z; ((ushort4*)out)[1] = z; return;
  }
  const float* s = src + (size_t)rr * HIDN + col0;
#pragma unroll
  for (int i = 0; i < 2; ++i) {
    float4 v = ((const float4*)s)[i];
    ushort4 o; o.x = f2bf(v.x); o.y = f2bf(v.y); o.z = f2bf(v.z); o.w = f2bf(v.w);
    ((ushort4*)out)[i] = o;
  }
}

// ---------------- bf16 GEMM: C(MxN) = A(MxK) @ B(NxK)^T (R4/R6 best) ----------------
template<int OBF16>
__global__ __launch_bounds__(256)
void k_gemm_bt(const u16* __restrict__ A, const u16* __restrict__ Bm,
               void* __restrict__ Cv, int M, int N, int K) {
  __shared__ u16 lA[2][128 * 32];
  __shared__ u16 lB[2][128 * 32];
  const int tid = threadIdx.x;
  const int wid = tid >> 6, lane = tid & 63;
  const int l15 = lane & 15, g = lane >> 4;
  const int nwg = gridDim.x * gridDim.y;
  int wg = xcd_swz(blockIdx.y * gridDim.x + blockIdx.x, nwg);
  const int m0 = (wg / gridDim.x) * 128, n0 = (wg % gridDim.x) * 128;
  const int wr = wid >> 1, wc = wid & 1;
  f32x4 acc[4][4];
#pragma unroll
  for (int m = 0; m < 4; ++m)
#pragma unroll
    for (int n = 0; n < 4; ++n) acc[m][n] = (f32x4){0.f,0.f,0.f,0.f};
  const int NT = K >> 5;

  auto stage = [&](int buf, int kt) {
    const int k0 = kt << 5;
#pragma unroll
    for (int i = 0; i < 2; ++i) {
      const int u = i * 256 + tid;
      const int row = u >> 2, cs = u & 3;
      const int cc = cs ^ ((row >> 1) & 3);
      gl_lds16(A  + (size_t)(m0 + row) * K + k0 + cc * 8, &lA[buf][(i*256 + wid*64) * 8]);
      gl_lds16(Bm + (size_t)(n0 + row) * K + k0 + cc * 8, &lB[buf][(i*256 + wid*64) * 8]);
    }
  };

  stage(0, 0);
  int cur = 0;
  for (int kt = 0; kt < NT; ++kt) {
    __syncthreads();
    if (kt + 1 < NT) stage(cur ^ 1, kt + 1);
    bf16x8 af[4], bfr[4];
#pragma unroll
    for (int m = 0; m < 4; ++m) {
      const int row = wr*64 + m*16 + l15;
      const int cc = g ^ ((row >> 1) & 3);
      af[m] = *(const bf16x8*)&lA[cur][row*32 + cc*8];
    }
#pragma unroll
    for (int n = 0; n < 4; ++n) {
      const int row = wc*64 + n*16 + l15;
      const int cc = g ^ ((row >> 1) & 3);
      bfr[n] = *(const bf16x8*)&lB[cur][row*32 + cc*8];
    }
    __builtin_amdgcn_s_setprio(1);
#pragma unroll
    for (int m = 0; m < 4; ++m)
#pragma unroll
      for (int n = 0; n < 4; ++n)
        acc[m][n] = __builtin_amdgcn_mfma_f32_16x16x32_bf16(af[m], bfr[n], acc[m][n], 0, 0, 0);
    __builtin_amdgcn_s_setprio(0);
    cur ^= 1;
  }
#pragma unroll
  for (int m = 0; m < 4; ++m)
#pragma unroll
    for (int n = 0; n < 4; ++n)
#pragma unroll
      for (int j = 0; j < 4; ++j) {
        const int row = m0 + wr*64 + m*16 + g*4 + j;
        const int col = n0 + wc*64 + n*16 + l15;
        if constexpr (OBF16) ((u16*)Cv)[(size_t)row * N + col] = f2bf(acc[m][n][j]);
        else                 ((float*)Cv)[(size_t)row * N + col] = acc[m][n][j];
      }
}

// ---------------- RoPE + rank-contract + RMSNorm -> q,k,v (bf16) ----------------
__global__ __launch_bounds__(256)
void k_qkv(const u16* __restrict__ Y, const float* __restrict__ cosT,
           const float* __restrict__ sinT, const float* __restrict__ qw,
           const float* __restrict__ kw, u16* __restrict__ q_s,
           u16* __restrict__ k_s, u16* __restrict__ v_s) {
  const int s = blockIdx.x;
  const int d = threadIdx.x;
  __shared__ float row[NPROJ];
  __shared__ float red[12][4];
  const u16* yr = Y + (size_t)s * NPROJP;
  for (int u4 = d; u4 < NPROJ/4; u4 += 256) {
    ushort4 v4 = ((const ushort4*)yr)[u4];
    row[u4*4+0] = bf2f(v4.x); row[u4*4+1] = bf2f(v4.y);
    row[u4*4+2] = bf2f(v4.z); row[u4*4+3] = bf2f(v4.w);
  }
  __syncthreads();
  const int i = d >> 1;
  const float cf = cosT[s * 128 + i];
  const float sf = sinT[s * 128 + i];
  const bool odd = d & 1;
  float bq[6], bk[2], bv[2];
#pragma unroll
  for (int r = 0; r < 6; ++r) {
    float x1 = row[64 + r*256 + 2*i], x2 = row[64 + r*256 + 2*i + 1];
    bq[r] = odd ? (x1*sf + x2*cf) : (x1*cf - x2*sf);
  }
#pragma unroll
  for (int r = 0; r < 2; ++r) {
    float x1 = row[1600 + r*256 + 2*i], x2 = row[1600 + r*256 + 2*i + 1];
    bk[r] = odd ? (x1*sf + x2*cf) : (x1*cf - x2*sf);
    bv[r] = row[2112 + r*256 + d];
  }
  float qv[8], kv[4], vv[4];
#pragma unroll
  for (int h = 0; h < 8; ++h) {
    float a = 0.f;
#pragma unroll
    for (int r = 0; r < 6; ++r) a += row[h*6 + r] * bq[r];
    qv[h] = a * (1.0f / 6.0f);
  }
#pragma unroll
  for (int c = 0; c < 4; ++c) {
    kv[c] = (row[48 + c*2]*bk[0] + row[48 + c*2 + 1]*bk[1]) * 0.5f;
    vv[c] = (row[56 + c*2]*bv[0] + row[56 + c*2 + 1]*bv[1]) * 0.5f;
  }
  const int lane = d & 63, wv = d >> 6;
#pragma unroll
  for (int t = 0; t < 12; ++t) {
    float x = (t < 8) ? qv[t] : kv[t - 8];
    float ss = x * x;
#pragma unroll
    for (int off = 32; off > 0; off >>= 1) ss += __shfl_xor(ss, off);
    if (lane == 0) red[t][wv] = ss;
  }
  __syncthreads();
  const float qwf = 1.0f + qw[d], kwf = 1.0f + kw[d];
#pragma unroll
  for (int h = 0; h < 8; ++h) {
    float v = red[h][0] + red[h][1] + red[h][2] + red[h][3];
    float r = rsqrtf(v * (1.0f/256.0f) + 1e-6f);
    q_s[((size_t)s*8 + h)*256 + d] = f2bf(qv[h] * r * qwf * 0.0625f);  // fold SCALING
  }
#pragma unroll
  for (int c = 0; c < 4; ++c) {
    float v = red[8+c][0] + red[8+c][1] + red[8+c][2] + red[8+c][3];
    float r = rsqrtf(v * (1.0f/256.0f) + 1e-6f);
    k_s[((size_t)s*4 + c)*256 + d] = f2bf(kv[c] * r * kwf);
    v_s[((size_t)s*4 + c)*256 + d] = f2bf(vv[c]);
  }
}

// ---------------- v (s,c,d) -> vT (c,d,s) 64x64 tile transpose ----------------
__global__ __launch_bounds__(256)
void k_vt(const u16* __restrict__ v_s, u16* __restrict__ vT) {
  __shared__ u16 tile[64][72];
  const int s0 = blockIdx.x * 64, d0 = blockIdx.y * 64, c = blockIdx.z;
  const int tid = threadIdx.x;
#pragma unroll
  for (int it = 0; it < 2; ++it) {
    const int u = it * 256 + tid;
    const int r = u >> 3, cc = u & 7;
    const u16* s = &v_s[(((size_t)(s0 + r))*4 + c)*256 + d0 + cc*8];
    ushort4 a = *(const ushort4*)s, b = *(const ushort4*)(s + 4);
    tile[r][cc*8+0]=a.x; tile[r][cc*8+1]=a.y; tile[r][cc*8+2]=a.z; tile[r][cc*8+3]=a.w;
    tile[r][cc*8+4]=b.x; tile[r][cc*8+5]=b.y; tile[r][cc*8+6]=b.z; tile[r][cc*8+7]=b.w;
  }
  __syncthreads();
#pragma unroll
  for (int it = 0; it < 2; ++it) {
    const int u = it * 256 + tid;
    const int dr = u >> 3, sc = u & 7;
    ushort4 a, b;
    a.x = tile[sc*8+0][dr]; a.y = tile[sc*8+1][dr]; a.z = tile[sc*8+2][dr]; a.w = tile[sc*8+3][dr];
    b.x = tile[sc*8+4][dr]; b.y = tile[sc*8+5][dr]; b.z = tile[sc*8+6][dr]; b.w = tile[sc*8+7][dr];
    u16* o = vT + ((size_t)c*256 + d0 + dr)*SEQ + s0 + sc*8;
    *(ushort4*)o = a; *(ushort4*)(o + 4) = b;
  }
}

// ---------------- flash attention (R6 structure, best measured: 69 us) ----------------
// ONE 512-thread block per CU: 64 queries x 2 heads (GQA pair shares K/V),
// 8 waves (wid>>2 = head, wid&3 = 16-query subtile). KVBLK=64, dbuf K+V,
// one vmcnt(0)+s_barrier per 64-key round. LDS 145 KB (1 block/CU).
__global__ __launch_bounds__(512, 2)
void k_attn(const u16* __restrict__ q_s, const u16* __restrict__ k_s,
            const u16* __restrict__ vT, const int* __restrict__ idx,
            u16* __restrict__ ao) {
  __shared__ u16 Kt[2][64 * 256];   // 32 KB x2
  __shared__ u16 Vt[2][256 * 64];   // 32 KB x2
  __shared__ u16 Pb[8][16 * 68];    // 17 KB wave-private P (16q x 64k, pad 4)
  const int b = blockIdx.x;
  const int c = b & 3, qt = b >> 2;           // c -> XCD affinity
  const int q0 = qt * 64;
  const int tid = threadIdx.x;
  const int wid = tid >> 6, lane = tid & 63;
  const int l15 = lane & 15, g = lane >> 4;
  const int h = 2*c + (wid >> 2);             // waves 0-3 -> head 2c; 4-7 -> 2c+1
  const int qsub = wid & 3;
  const int qrow = q0 + qsub*16 + l15;
  const int qpos = idx[qrow];

  bf16x8 qf[8];
  const u16* qb = q_s + ((size_t)qrow * 8 + h) * 256;
#pragma unroll
  for (int kk = 0; kk < 8; ++kk) qf[kk] = *(const bf16x8*)(qb + kk*32 + g*8);

  const int sw = l15 & 7;
  int kbase[8];
#pragma unroll
  for (int kk = 0; kk < 8; ++kk)
    kbase[kk] = l15*256 + ((((kk<<2)+g) ^ sw) << 3);   // + nk*4096 + kco
  u16* KtF = &Kt[0][0];
  u16* VtF = &Vt[0][0];
  u16* Pw  = &Pb[wid][0];

  f32x4 accO[16];
#pragma unroll
  for (int n = 0; n < 16; ++n) accO[n] = (f32x4){0.f,0.f,0.f,0.f};
  float mrun = -50.0f, lrun = 0.0f;           // per-lane partial lrun

  int t0 = q0 - (WIN - 1); if (t0 < 0) t0 = 0;
  const int kt_lo = t0 >> 6, kt_hi = qt;

  const u16* kgp = k_s + (size_t)(kt_lo*64 + (tid>>5)) * 1024 + c*256
                   + (((tid & 31) ^ ((tid >> 5) & 7)) << 3);
  const u16* vgp = vT + (size_t)c*1048576 + (size_t)(tid>>3)*4096 + kt_lo*64
                   + (((tid & 7) ^ ((tid >> 3) & 7)) << 3);

  auto stage = [&](int buf) {
#pragma unroll
    for (int i = 0; i < 4; ++i)
      gl_lds16(kgp + i*16384,  &Kt[buf][(i*512 + wid*64) * 8]);
#pragma unroll
    for (int i = 0; i < 4; ++i)
      gl_lds16(vgp + i*262144, &Vt[buf][(i*512 + wid*64) * 8]);
  };

  stage(0);
  int cur = 0;
  for (int kt = kt_lo; kt <= kt_hi; ++kt) {
    const int k0 = kt << 6;
    sync_vm();                                 // buf[cur] staged (issued 1 round ago)
    if (kt < kt_hi) { kgp += 65536; vgp += 64; stage(cur ^ 1); }

    // S^T = K @ Q^T : D[key = nk*16 + g*4+j][q = l15]
    const int kco = cur * 16384;
    f32x4 sc[4];
#pragma unroll
    for (int nk = 0; nk < 4; ++nk) sc[nk] = (f32x4){0.f,0.f,0.f,0.f};
    __builtin_amdgcn_s_setprio(1);
#pragma unroll
    for (int nk = 0; nk < 4; ++nk)
#pragma unroll
      for (int kk = 0; kk < 8; ++kk) {
        bf16x8 kf = *(const bf16x8*)&KtF[kco + nk*4096 + kbase[kk]];
        sc[nk] = __builtin_amdgcn_mfma_f32_16x16x32_bf16(kf, qf[kk], sc[nk], 0, 0, 0);
      }
    __builtin_amdgcn_s_setprio(0);

    // softcap: t = 50 - 100/(1+exp2(x*2*log2e/50))
    float tv[16];
#pragma unroll
    for (int nk = 0; nk < 4; ++nk)
#pragma unroll
      for (int j = 0; j < 4; ++j) {
        float u = __builtin_amdgcn_exp2f(sc[nk][j] * 0.05770780163555854f);
        tv[nk*4+j] = fmaf(-100.0f, __builtin_amdgcn_rcpf(1.0f + u), 50.0f);
      }
    if (kt == kt_hi) {                        // causal edge tile
#pragma unroll
      for (int nk = 0; nk < 4; ++nk)
#pragma unroll
        for (int j = 0; j < 4; ++j)
          if (k0 + nk*16 + g*4 + j > qpos) tv[nk*4+j] = -1e38f;
    } else if (kt == kt_lo) {                 // window edge tile
#pragma unroll
      for (int nk = 0; nk < 4; ++nk)
#pragma unroll
        for (int j = 0; j < 4; ++j)
          if (qpos - (k0 + nk*16 + g*4 + j) > 1023) tv[nk*4+j] = -1e38f;
    }

    float tmax = tv[0];
#pragma unroll
    for (int t = 1; t < 16; ++t) tmax = fmaxf(tmax, tv[t]);
    if (__any(tmax > mrun + 8.0f)) {          // defer-max: reduce only on trigger
      float tq = fmaxf(tmax, __shfl_xor(tmax, 16));
      tq = fmaxf(tq, __shfl_xor(tq, 32));
      const float mnew = fmaxf(mrun, tq);
      const float scale = __builtin_amdgcn_exp2f((mrun - mnew) * 1.442695041f);
      float scj[4];
#pragma unroll
      for (int j = 0; j < 4; ++j) scj[j] = __shfl(scale, g*4 + j);
#pragma unroll
      for (int n = 0; n < 16; ++n) {
        accO[n][0] *= scj[0]; accO[n][1] *= scj[1];
        accO[n][2] *= scj[2]; accO[n][3] *= scj[3];
      }
      lrun *= scale;
      mrun = mnew;
    }
    const float mr2 = mrun * 1.442695041f;
    float p[16];
#pragma unroll
    for (int t = 0; t < 16; ++t) {
      p[t] = __builtin_amdgcn_exp2f(fmaf(tv[t], 1.442695041f, -mr2));
      lrun += p[t];
    }

    // P -> wave-private LDS (bf16): key position nk*16+g*4..+3 of row l15
#pragma unroll
    for (int nk = 0; nk < 4; ++nk) {
      uint2 w = { cvtpk(p[nk*4+0], p[nk*4+1]), cvtpk(p[nk*4+2], p[nk*4+3]) };
      *(uint2*)&Pw[l15*68 + nk*16 + g*4] = w;
    }
    // O += P @ V : A-frag P[q=l15][k=half*32+g*8..], B-frag V^T[d=n*16+l15][k]
    const int vco = cur * 16384;
    __builtin_amdgcn_s_setprio(1);
#pragma unroll
    for (int half = 0; half < 2; ++half) {
      bf16x8 pa = *(const bf16x8*)&Pw[l15*68 + half*32 + g*8];
#pragma unroll
      for (int n = 0; n < 16; ++n) {
        bf16x8 vf = *(const bf16x8*)&VtF[vco + (n*16 + l15)*64
                                         + ((((half<<2)+g) ^ sw) << 3)];
        accO[n] = __builtin_amdgcn_mfma_f32_16x16x32_bf16(pa, vf, accO[n], 0, 0, 0);
      }
    }
    __builtin_amdgcn_s_setprio(0);
    cur ^= 1;
  }

  lrun += __shfl_xor(lrun, 16);
  lrun += __shfl_xor(lrun, 32);
  const float linv = __builtin_amdgcn_rcpf(lrun);
  float lj[4];
#pragma unroll
  for (int j = 0; j < 4; ++j) lj[j] = __shfl(linv, g*4 + j);
#pragma unroll
  for (int n = 0; n < 16; ++n)
#pragma unroll
    for (int j = 0; j < 4; ++j) {
      const int r = q0 + qsub*16 + g*4 + j;
      ao[(size_t)r * HIDN + h*256 + n*16 + l15] = f2bf(accO[n][j] * lj[j]);
    }
}

// ---------------- launch ----------------
extern "C" void kernel_launch(void* const* d_in, const int* in_sizes, int n_in,
                              void* d_out, int out_size, void* d_ws, size_t ws_size,
                              hipStream_t stream) {
  const float* x    = (const float*)d_in[0];
  const float* fcos = (const float*)d_in[1];
  const float* fsin = (const float*)d_in[2];
  const float* waq  = (const float*)d_in[3];
  const float* wak  = (const float*)d_in[4];
  const float* wav  = (const float*)d_in[5];
  const float* wbq  = (const float*)d_in[6];
  const float* wbk  = (const float*)d_in[7];
  const float* wbv  = (const float*)d_in[8];
  const float* wo   = (const float*)d_in[9];
  const float* qnw  = (const float*)d_in[10];
  const float* knw  = (const float*)d_in[11];
  const int*   idx  = (const int*)d_in[16];
  float* out = (float*)d_out;

  char* p = (char*)d_ws;
  u16*  xb   = (u16*)p;                 p += (size_t)SEQ*HIDN*2;
  u16*  wcat = (u16*)p;                 p += (size_t)NPROJP*HIDN*2;
  u16*  wob  = (u16*)p;                 p += (size_t)HIDN*HIDN*2;
  u16*  ypr  = (u16*)p;                 p += (size_t)SEQ*NPROJP*2;     // proj out bf16
  u16*  q_s  = (u16*)p;                 p += (size_t)SEQ*NHEAD*DH*2;
  u16*  k_s  = (u16*)p;                 p += (size_t)SEQ*NKVH*DH*2;
  u16*  v_s  = (u16*)p;                 p += (size_t)SEQ*NKVH*DH*2;
  u16*  vT   = (u16*)p;                 p += (size_t)SEQ*NKVH*DH*2;
  u16*  ao   = (u16*)p;                 p += (size_t)SEQ*HIDN*2;

  k_prep<<<14976, 256, 0, stream>>>(x, xb, wo, wob, waq, wak, wav, wbq, wbk, wbv, wcat);
  k_gemm_bt<1><<<dim3(NPROJP/128, SEQ/128), 256, 0, stream>>>(xb, wcat, ypr, SEQ, NPROJP, HIDN);
  k_qkv <<<SEQ, 256, 0, stream>>>(ypr, fcos, fsin, qnw, knw, q_s, k_s, v_s);
  k_vt  <<<dim3(SEQ/64, DH/64, NKVH), 256, 0, stream>>>(v_s, vT);
  k_attn<<<dim3(SEQ/64 * NKVH), 512, 0, stream>>>(q_s, k_s, vT, idx, ao);
  k_gemm_bt<0><<<dim3(HIDN/128, SEQ/128), 256, 0, stream>>>(ao, wob, out, SEQ, HIDN, HIDN);
}